// Round 12
// baseline (43.367 us; speedup 1.0000x reference)
//
#include <hip/hip_runtime.h>
#include <cmath>

// Noisy 8-qubit density-matrix sim, batch 32, depth 6 — lightcone adjoint, WAVE-LOCAL runs.
// E_b = Tr(Λ†(Z0)·rho_b); CPTP adjoints unital => 21 nontrivial stages; qubit 7 never enters.
// Kernel 1 (1 block, 1024 thr): backward-evolve O in LDS. Kernel 2 (32 blocks): contract.
// NEW vs round 11: stages grouped into wave-local runs. A wave owns the 256-el set where
// 4 fixed "wave-id" positions match its id; a run of stages whose active positions avoid
// those wave positions needs NO __syncthreads internally (same-wave LDS ordering via
// lgkmcnt; ownership partitions the slab). Map A (U=1,2,3): wave -> {4,5,10,11};
// map B (U=4,5): wave -> {0,1,6,7}. 15-stage sequence = runs B3,A1,B2,A2,B2,A3,B2;
// tail = expand(B-local), full T†(5,0), A3, B2. Block barriers: 22 -> 11.
// astage_q4 / astage_full / swizzle / contract verbatim from round 11 (absmax 0).

typedef float2 cplx;
#define BATCH 32

__device__ __forceinline__ cplx cmul(cplx a, cplx b){
  return make_float2(a.x*b.x - a.y*b.y, a.x*b.y + a.y*b.x);
}
__device__ __forceinline__ cplx lc(float a, cplx u, float b, cplx v){
  return make_float2(a*u.x + b*v.x, a*u.y + b*v.y);
}
__device__ __forceinline__ cplx sc(float a, cplx u){ return make_float2(a*u.x, a*u.y); }

struct N1C { float A,B,C,D,E; };
__device__ __forceinline__ N1C noise_coeffs(float g){
  float ga = g*0.3f, gp = g*0.2f, p = g*0.5f;
  N1C n;
  n.A = 1.0f - 2.0f*p/3.0f;
  n.D = 2.0f*p/3.0f;
  n.B = ga*n.A + n.D*(1.0f-ga);
  n.E = n.D*ga + n.A*(1.0f-ga);
  n.C = (1.0f - 4.0f*p/3.0f) * sqrtf(1.0f-ga) * sqrtf(1.0f-gp);
  return n;
}
__device__ __forceinline__ N1C mkadj(N1C n){
  N1C a; a.A=n.A; a.B=n.D; a.C=n.C; a.D=n.B; a.E=n.E; return a;
}

__device__ __forceinline__ int physof(int L){
  int rl = L >> 6;
  int rot = ((rl<<3)|(rl>>3)) & 63;
  return L ^ rot;
}
__device__ __forceinline__ constexpr int KPc(int p){
  return (p < 6) ? (1<<p) : ((1<<p) | (1 << (((p-6)+3)%6)));
}

// wave-local split tables: lane = (g<<2)|(bsel<<1)|dsel, g = t>>2 (bits 0..3 lane, 4..7 wave).
// U<=3 (map A): wave bits -> positions {4,5,10,11}. U>=4 (map B): wave -> {0,1,6,7}.
// Coverage check per U: P row + active {U-1,U,5+U,6+U} = all 12 positions exactly once.
template<int U>
__device__ __forceinline__ int base4(int g){
  constexpr int P[6][8] = {
    {0,0,0,0,0,0,0,0},
    {2,3,8,9,  4,5,10,11},   // U=1 A (active {0,1,6,7})
    {0,3,6,9,  4,5,10,11},   // U=2 A (active {1,2,7,8})
    {0,1,6,7,  4,5,10,11},   // U=3 A (active {2,3,8,9})
    {2,5,8,11, 0,1,6,7},     // U=4 B (active {3,4,9,10})
    {2,3,8,9,  0,1,6,7}};    // U=5 B (active {4,5,10,11})
  int b = 0;
  #pragma unroll
  for (int i=0;i<8;i++) b ^= (-((g>>i)&1)) & KPc(P[U][i]);
  return b;
}

// free bits for T†(5,0) full-16 stage (10 bits over positions <=11 + raw bits 12,13)
__device__ __forceinline__ int base_s(int t){
  constexpr int P[10] = {1,2,3,9, 4,5,7,8,10,11};
  int b = 0;
  #pragma unroll
  for (int i=0;i<10;i++) b ^= (-((t>>i)&1)) & KPc(P[i]);
  return b;
}

__device__ __forceinline__ void rot_pair(cplx& v0, cplx& v1, float cy, float sy){
  cplx a=v0, b=v1;
  v0 = make_float2(cy*a.x - sy*b.x, cy*a.y - sy*b.y);
  v1 = make_float2(sy*a.x + cy*b.x, sy*a.y + cy*b.y);
}

// ---------------- 4-way adjoint stage (round-11 verbatim): thread owns (b,d)=(bsel,dsel) ----------------
template<int U>
__device__ __forceinline__ void astage_q4(cplx* __restrict__ slab, float4 rc, int bp,
                                          int bsel, int dsel, N1C n1a, N1C n2a,
                                          float alpha, float beta){
  constexpr int KA=KPc(6+U), KB=KPc(5+U), KC=1<<U, KD=1<<(U-1);
  int fix = (bsel?KB:0) ^ (dsel?KD:0);
  cplx v[4];
  v[0] = slab[bp ^ fix];
  v[1] = slab[bp ^ fix ^ KC];
  v[2] = slab[bp ^ fix ^ KA];
  v[3] = slab[bp ^ fix ^ KA ^ KC];
  cplx p  = make_float2(rc.z, -rc.w);
  cplx pc = make_float2(rc.z,  rc.w);
  float cy=rc.x, sy=-rc.y;
  {
    cplx t00=v[0], t11=v[3];
    v[0]=lc(n1a.A,t00, n1a.B,t11);
    v[3]=lc(n1a.D,t00, n1a.E,t11);
    v[1]=cmul(p,v[1]); v[2]=cmul(pc,v[2]);
    rot_pair(v[0],v[1],cy,sy); rot_pair(v[2],v[3],cy,sy);
    rot_pair(v[0],v[2],cy,sy); rot_pair(v[1],v[3],cy,sy);
  }
  #pragma unroll
  for (int j=0;j<4;j++){
    float rx = __shfl_xor(v[j].x, 3, 64);
    float ry = __shfl_xor(v[j].y, 3, 64);
    v[j] = make_float2(alpha*v[j].x + beta*rx, alpha*v[j].y + beta*ry);
  }
  {
    cplx t00=v[0], t11=v[3];
    v[0]=lc(n2a.A,t00, n2a.B,t11);
    v[3]=lc(n2a.D,t00, n2a.E,t11);
    v[1]=sc(n2a.C,v[1]); v[2]=sc(n2a.C,v[2]);
  }
  int sb = bsel ? KB : 0;
  slab[bp ^ sb            ^ (dsel?KD:0)]      = v[0];
  slab[bp ^ sb ^ KC       ^ (dsel?0:KD)]      = v[1];
  slab[bp ^ (sb^KB) ^ KA  ^ (dsel?KD:0)]      = v[2];
  slab[bp ^ (sb^KB) ^ KA ^ KC ^ (dsel?0:KD)]  = v[3];
}

// ---------------- full-16 adjoint stage, general masks (round-9 verbatim) ----------------
template<int KA,int KB,int KC,int KD>
__device__ __forceinline__ void astage_full(cplx* __restrict__ slab, float4 rc,
                                            int bp, N1C n1a, N1C n2a){
  cplx h[16];
  #pragma unroll
  for (int idx=0; idx<16; idx++){
    int a=(idx>>3)&1, b=(idx>>2)&1, cc=(idx>>1)&1, d=idx&1;
    h[idx] = slab[bp ^ (a?KA:0) ^ (b?KB:0) ^ (cc?KC:0) ^ (d?KD:0)];
  }
  {
    cplx p=make_float2(rc.z,-rc.w), pc=make_float2(rc.z,rc.w);
    #pragma unroll
    for (int b=0;b<2;b++)
      #pragma unroll
      for (int d=0;d<2;d++){
        int i=(b<<2)|d;
        cplx t00=h[i], t11=h[i|10];
        h[i]    = lc(n1a.A,t00, n1a.B,t11);
        h[i|10] = lc(n1a.D,t00, n1a.E,t11);
        h[i|2]  = cmul(p,  h[i|2]);
        h[i|8]  = cmul(pc, h[i|8]);
      }
    float cy=rc.x, sy=-rc.y;
    #pragma unroll
    for (int a=0;a<2;a++)
      #pragma unroll
      for (int b=0;b<2;b++)
        #pragma unroll
        for (int d=0;d<2;d++){
          int i=(a<<3)|(b<<2)|d;
          rot_pair(h[i], h[i|2], cy, sy);
        }
    #pragma unroll
    for (int b=0;b<2;b++)
      #pragma unroll
      for (int cc=0;cc<2;cc++)
        #pragma unroll
        for (int d=0;d<2;d++){
          int i=(b<<2)|(cc<<1)|d;
          rot_pair(h[i], h[i|8], cy, sy);
        }
  }
  #pragma unroll
  for (int a=0;a<2;a++)
    #pragma unroll
    for (int cc=0;cc<2;cc++){
      int i=(a<<3)|(cc<<1);
      cplx t00=h[i], t11=h[i|5];
      h[i]   = lc(n2a.A,t00, n2a.B,t11);
      h[i|5] = lc(n2a.D,t00, n2a.E,t11);
      h[i|1] = sc(n2a.C, h[i|1]);
      h[i|4] = sc(n2a.C, h[i|4]);
    }
  #pragma unroll
  for (int b=0;b<2;b++)
    #pragma unroll
    for (int d=0;d<2;d++){
      int i=(b<<2)|d;
      cplx t00=h[i], t11=h[i|10];
      h[i]    = lc(n2a.A,t00, n2a.B,t11);
      h[i|10] = lc(n2a.D,t00, n2a.E,t11);
      h[i|2]  = sc(n2a.C, h[i|2]);
      h[i|8]  = sc(n2a.C, h[i|8]);
    }
  #pragma unroll
  for (int idx=0; idx<16; idx++){
    int a=(idx>>3)&1, b=(idx>>2)&1, cc=(idx>>1)&1, d=idx&1;
    slab[bp ^ (a?KA:0) ^ ((b^a)?KB:0) ^ (cc?KC:0) ^ ((d^cc)?KD:0)] = h[idx];
  }
}

// stage without barrier (wave-local); barriers placed explicitly at run transitions
#define SQ(l,q,u)  astage_q4<u>(slab, sS[(l)*8+(q)], b##u, bsel, dsel, n1a, n2a, alpha, beta);
#define SQB(q,u)   { _Pragma("unroll") \
                     for (int sub=0; sub<4; sub++) \
                       astage_q4<u>(slab + (sub<<12), sS[(q)], b##u, bsel, dsel, n1a, n2a, alpha, beta); }

// ---------------- backward pass: one block, 1024 threads ----------------
__global__ __launch_bounds__(1024) void backward_kernel(const float* __restrict__ w,
                                                        float* __restrict__ Og){
  __shared__ cplx slab[16384];      // 128 KB
  __shared__ float4 sS[48];
  int t = threadIdx.x;
  int dsel = t & 1, bsel = (t >> 1) & 1;
  int gg = t >> 2;                  // bits 0..3 = lane, 4..7 = wave id
  N1C n1a = mkadj(noise_coeffs(0.0003f));
  N1C n2a = mkadj(noise_coeffs(0.0065f));
  float alpha = (bsel==dsel) ? (bsel ? n2a.E : n2a.A) : n2a.C;
  float beta  = (bsel==dsel) ? (bsel ? n2a.D : n2a.B) : 0.f;
  int b1=base4<1>(gg), b2=base4<2>(gg), b3=base4<3>(gg),
      b4=base4<4>(gg), b5=base4<5>(gg);
  (void)b1;(void)b2;(void)b3;(void)b4;(void)b5;

  if (t < 48){
    N1C n1 = noise_coeffs(0.0003f);
    float w0=w[t*2], w1=w[t*2+1];
    sS[t] = make_float4(cosf(0.5f*w0), sinf(0.5f*w0), n1.C*cosf(w1), -n1.C*sinf(w1));
  }
  // init O = Z0 ⊗ I on 6-qubit slab (qubit0 = row bit 5)
  #pragma unroll
  for (int i=0;i<4;i++){
    int L = i*1024 + t, rl = L>>6, cl = L&63;
    slab[physof(L)] = make_float2((rl==cl) ? ((rl&32)? -1.f : 1.f) : 0.f, 0.f);
  }
  __syncthreads();

  // 15 lightcone stages in 7 wave-local runs (barriers only at A<->B map transitions)
  SQ(5,0,5) SQ(4,1,4) SQ(4,0,5)            __syncthreads();   // B-run
  SQ(3,2,3)                                __syncthreads();   // A-run
  SQ(3,1,4) SQ(3,0,5)                      __syncthreads();   // B-run
  SQ(2,3,2) SQ(2,2,3)                      __syncthreads();   // A-run
  SQ(2,1,4) SQ(2,0,5)                      __syncthreads();   // B-run
  SQ(1,4,1) SQ(1,3,2) SQ(1,2,3)            __syncthreads();   // A-run
  SQ(1,1,4) SQ(1,0,5)                                         // B-run (flows into B-local expand)

  // expand to 7 qubits (wave-local in map B: wave bits at positions {0,1,6,7})
  {
    int wv = t >> 6, ln = t & 63;
    int Lbase = ((wv&1))|((wv>>1&1)<<1)|((ln&1)<<2)|((ln>>1&1)<<3)|((ln>>2&1)<<4)
              |((ln>>3&1)<<5)|((wv>>2&1)<<6)|((wv>>3&1)<<7)|((ln>>4&1)<<8)|((ln>>5&1)<<9);
    #pragma unroll
    for (int i=0;i<4;i++){
      int ph = physof(Lbase | ((i&1)<<10) | ((i>>1)<<11));
      cplx v = slab[ph];
      slab[(3<<12)|ph] = v;
      slab[(1<<12)|ph] = make_float2(0.f,0.f);
      slab[(2<<12)|ph] = make_float2(0.f,0.f);
    }
  }
  __syncthreads();

  // T†(5,0): qubit5 (ctl) x qubit6 (tgt, bits 13/12) — crosses waves
  astage_full<KPc(6), (1<<13), 1, (1<<12)>(slab, sS[5], base_s(t), n1a, n2a);
  __syncthreads();

  // tail: layer-0 stages block-diagonal in qubit 6, wave-local runs
  SQB(4,1) SQB(3,2) SQB(2,3)               __syncthreads();   // A-run
  SQB(1,4) SQB(0,5)                        __syncthreads();   // B-run

  // write Re(O)
  #pragma unroll
  for (int i=0;i<16;i++){
    int el = i*1024 + t;
    Og[el] = slab[(el & (3<<12)) | physof(el & 4095)].x;
  }
}

// ---------------- contraction (round-9 verbatim) ----------------
__global__ __launch_bounds__(256) void contract_kernel(const float* __restrict__ Og,
                                                       const float* __restrict__ x,
                                                       float* __restrict__ out){
  __shared__ float sm[28];
  __shared__ float red[4];
  int t = threadIdx.x, s = blockIdx.x;
  if (t < 7){
    N1C n1 = noise_coeffs(0.0003f);
    float xv = x[s*8+t];
    float c = cosf(0.5f*xv), sn = sinf(0.5f*xv);
    float p00=c*c, p01=c*sn, p11=sn*sn;
    sm[t*4+0]=n1.A*p00+n1.B*p11; sm[t*4+1]=n1.C*p01;
    sm[t*4+2]=n1.C*p01;          sm[t*4+3]=n1.D*p00+n1.E*p11;
  }
  __syncthreads();
  int cl = t & 63;
  int r45 = t >> 6;
  float w0;
  {
    int c4=(cl>>1)&1, c5=cl&1;
    w0 = sm[16 + ((r45>>1)&1)*2 + c4] * sm[20 + (r45&1)*2 + c5];
  }
  int c0=(cl>>5)&1, c1=(cl>>4)&1, c2=(cl>>3)&1, c3=(cl>>2)&1;
  float g0[2]={sm[0+c0],  sm[2+c0]};
  float g1[2]={sm[4+c1],  sm[6+c1]};
  float g2[2]={sm[8+c2],  sm[10+c2]};
  float g3[2]={sm[12+c3], sm[14+c3]};
  float m6v[4]={sm[24], sm[25], sm[26], sm[27]};
  float acc = 0.f;
  #pragma unroll
  for (int i=0;i<64;i++){
    int el = i*256 + t;
    float wq = w0 * g0[(i>>3)&1] * g1[(i>>2)&1] * g2[(i>>1)&1] * g3[i&1] * m6v[i>>4];
    acc += Og[el] * wq;
  }
  #pragma unroll
  for (int off=32; off>0; off>>=1) acc += __shfl_down(acc, off, 64);
  if ((t&63)==0) red[t>>6] = acc;
  __syncthreads();
  if (t==0) out[s] = red[0]+red[1]+red[2]+red[3];
}

extern "C" void kernel_launch(void* const* d_in, const int* in_sizes, int n_in,
                              void* d_out, int out_size, void* d_ws, size_t ws_size,
                              hipStream_t stream) {
  const float* x = (const float*)d_in[0];   // [32,8]
  const float* w = (const float*)d_in[1];   // [6,8,2]
  float* out = (float*)d_out;               // [32,1] f32
  float* Og  = (float*)d_ws;                // 64 KB: Re(O), 7-qubit operator

  backward_kernel<<<1, 1024, 0, stream>>>(w, Og);
  contract_kernel<<<BATCH, 256, 0, stream>>>(Og, x, out);
}